// Round 1
// baseline (416.766 us; speedup 1.0000x reference)
//
#include <hip/hip_runtime.h>

#define LN_EPS 1e-5f

__device__ __forceinline__ float wsum(float v) {
    #pragma unroll
    for (int off = 32; off; off >>= 1) v += __shfl_xor(v, off, 64);
    return v;
}
__device__ __forceinline__ float wmax(float v) {
    #pragma unroll
    for (int off = 32; off; off >>= 1) v = fmaxf(v, __shfl_xor(v, off, 64));
    return v;
}

// Kernel 1: xn = LayerNorm(emb); a_i = xn @ W1[0:64]; a_j = xn @ W1[64:128]
// One wave per row (bs*n = 8192 rows), 4 waves/block.
__global__ __launch_bounds__(256) void att1_precompute(
    const float* __restrict__ emb, const float* __restrict__ g,
    const float* __restrict__ bln, const float* __restrict__ W1,
    float* __restrict__ ai, float* __restrict__ aj)
{
    __shared__ float w_s[8192];   // W1 rows 0..127 (a_i block then a_j block)
    __shared__ float xn_s[4][64];

    const int tid = threadIdx.x, lane = tid & 63, wid = tid >> 6;
    for (int i = tid; i < 8192; i += 256) w_s[i] = W1[i];

    const int r = blockIdx.x * 4 + wid;          // row in [0, 8192)
    float x = emb[r * 64 + lane];
    float mu = wsum(x) * (1.f / 64.f);
    float xc = x - mu;
    float var = wsum(xc * xc) * (1.f / 64.f);
    float rsig = rsqrtf(var + LN_EPS);
    float xn = xc * rsig * g[lane] + bln[lane];
    xn_s[wid][lane] = xn;
    __syncthreads();

    float a0 = 0.f, a1 = 0.f;
    #pragma unroll
    for (int k = 0; k < 64; ++k) {
        float xnk = xn_s[wid][k];                // LDS broadcast
        a0 = fmaf(xnk, w_s[k * 64 + lane], a0);
        a1 = fmaf(xnk, w_s[(64 + k) * 64 + lane], a1);
    }
    ai[r * 64 + lane] = a0;
    aj[r * 64 + lane] = a1;
}

// Kernel 2: fully fused pairwise attention. One block per (b,p).
// 4 waves x 64 lanes; wave w handles q = w, w+4, ...
__global__ __launch_bounds__(256) void att1_main(
    const float* __restrict__ emb, const float* __restrict__ g,
    const float* __restrict__ bln, const float* __restrict__ W1,
    const float* __restrict__ b1, const float* __restrict__ W2,
    const float* __restrict__ b2, const float* __restrict__ ai,
    const float* __restrict__ aj, float* __restrict__ out)
{
    __shared__ float xb_s[128 * 64];   // 32 KB: all rows of emb[b]
    __shared__ float w_s[64 * 64];     // 16 KB: W1 rows 128..191 (em_ij block)
    __shared__ float g_s[64], bln_s[64];
    __shared__ float scores_s[128];
    __shared__ float red_s[4][64];

    const int tid = threadIdx.x, lane = tid & 63, wid = tid >> 6;
    const int p = blockIdx.x, b = blockIdx.y;

    const float* embB = emb + b * 128 * 64;
    for (int i = tid; i < 8192; i += 256) xb_s[i] = embB[i];
    for (int i = tid; i < 4096; i += 256) w_s[i] = W1[128 * 64 + i];
    if (tid < 64) { g_s[tid] = g[tid]; bln_s[tid] = bln[tid]; }
    __syncthreads();

    const float xp  = xb_s[p * 64 + lane];
    const float ajp = aj[(b * 128 + p) * 64 + lane];
    const float b1l = b1[lane];
    const float w2l = W2[lane];
    const float b2s = b2[0];

    // Per-lane column d of U[k,d] = x_p[k] * g[k] * Wij[k,d]  (registers)
    // S[d] = sum_k g[k]*Wij[k,d];  c1[d] = sum_k b_ln[k]*Wij[k,d]
    float U[64];
    float S = 0.f, c1 = 0.f;
    #pragma unroll
    for (int k = 0; k < 64; ++k) {
        float wkd = w_s[k * 64 + lane];
        float t = g_s[k] * wkd;                  // broadcast * coalesced
        U[k] = xb_s[p * 64 + k] * t;             // broadcast
        S += t;
        c1 = fmaf(bln_s[k], wkd, c1);
    }

    for (int q = wid; q < 128; q += 4) {
        const float* xq_row = xb_s + q * 64;
        float xq = xq_row[lane];
        float v = xp * xq;
        float sv = v, sv2 = v * v;
        #pragma unroll
        for (int off = 32; off; off >>= 1) {
            sv  += __shfl_xor(sv, off, 64);
            sv2 += __shfl_xor(sv2, off, 64);
        }
        float mu = sv * (1.f / 64.f);
        float var = sv2 * (1.f / 64.f) - mu * mu;
        float rsig = rsqrtf(var + LN_EPS);

        // raw[d] = sum_k x_q[k] * U[k]   (b128 broadcasts + register FMAs)
        float acc = 0.f;
        #pragma unroll
        for (int k4 = 0; k4 < 16; ++k4) {
            float4 xv = ((const float4*)xq_row)[k4];
            acc = fmaf(xv.x, U[k4 * 4 + 0], acc);
            acc = fmaf(xv.y, U[k4 * 4 + 1], acc);
            acc = fmaf(xv.z, U[k4 * 4 + 2], acc);
            acc = fmaf(xv.w, U[k4 * 4 + 3], acc);
        }
        float a_ij = rsig * (acc - mu * S) + c1;

        float aiq = ai[(b * 128 + q) * 64 + lane];
        float xatt = aiq + ajp + a_ij + b1l;
        xatt = fminf(fmaxf(xatt, -10.f), 10.f);
        float e = __expf(2.f * xatt);
        float th = (e - 1.f) / (e + 1.f);        // tanh
        float sc = wsum(th * w2l) + b2s;
        if (lane == 0) scores_s[q] = sc;
    }
    __syncthreads();

    // Softmax over 128 scores, computed redundantly per wave (no extra barrier)
    float s0 = scores_s[lane], s1 = scores_s[64 + lane];
    float M = wmax(fmaxf(s0, s1));
    float Z = wsum(__expf(s0 - M) + __expf(s1 - M));
    float rZ = 1.f / Z;

    // out[d] = sum_q alpha_q * leaky_relu(x_p[d]*x_q[d])   (alpha > 0)
    float accd = 0.f;
    for (int q = wid; q < 128; q += 4) {
        float alpha = __expf(scores_s[q] - M) * rZ;
        float w = xp * xb_s[q * 64 + lane];
        float lr = w > 0.f ? w : 0.01f * w;
        accd = fmaf(alpha, lr, accd);
    }
    red_s[wid][lane] = accd;
    __syncthreads();
    if (wid == 0) {
        float o = red_s[0][lane] + red_s[1][lane] + red_s[2][lane] + red_s[3][lane];
        out[(b * 128 + p) * 64 + lane] = o;
    }
}

extern "C" void kernel_launch(void* const* d_in, const int* in_sizes, int n_in,
                              void* d_out, int out_size, void* d_ws, size_t ws_size,
                              hipStream_t stream) {
    const float* emb = (const float*)d_in[0];   // [64,128,64]
    const float* g   = (const float*)d_in[1];   // [64]
    const float* bln = (const float*)d_in[2];   // [64]
    const float* W1  = (const float*)d_in[3];   // [192,64]
    const float* b1  = (const float*)d_in[4];   // [64]
    const float* W2  = (const float*)d_in[5];   // [64,1]
    const float* b2  = (const float*)d_in[6];   // [1]
    float* out = (float*)d_out;

    float* ws = (float*)d_ws;
    float* ai = ws;                 // 64*128*64 floats = 2 MB
    float* aj = ws + 64 * 128 * 64; // 2 MB

    att1_precompute<<<2048, 256, 0, stream>>>(emb, g, bln, W1, ai, aj);
    att1_main<<<dim3(128, 64), 256, 0, stream>>>(emb, g, bln, W1, b1, W2, b2, ai, aj, out);
}

// Round 2
// 159.862 us; speedup vs baseline: 2.6070x; 2.6070x over previous
//
#include <hip/hip_runtime.h>

#define LN_EPS 1e-5f

typedef __attribute__((ext_vector_type(8))) short bf16x8;
typedef __attribute__((ext_vector_type(4))) float f32x4;

__device__ __forceinline__ float wsum(float v) {
    #pragma unroll
    for (int off = 32; off; off >>= 1) v += __shfl_xor(v, off, 64);
    return v;
}
__device__ __forceinline__ float wmax(float v) {
    #pragma unroll
    for (int off = 32; off; off >>= 1) v = fmaxf(v, __shfl_xor(v, off, 64));
    return v;
}
// f32 -> bf16 round-to-nearest-even
__device__ __forceinline__ short f2bf(float f) {
    union { float f; unsigned u; } v; v.f = f;
    unsigned r = (v.u + 0x7FFFu + ((v.u >> 16) & 1u)) >> 16;
    return (short)r;
}

// ---------------- Kernel 1: xn = LN(emb); ai = xn@W1[0:64]; aj = xn@W1[64:128]
__global__ __launch_bounds__(256) void att1_precompute(
    const float* __restrict__ emb, const float* __restrict__ g,
    const float* __restrict__ bln, const float* __restrict__ W1,
    float* __restrict__ ai, float* __restrict__ aj)
{
    __shared__ float w_s[8192];
    __shared__ float xn_s[4][64];

    const int tid = threadIdx.x, lane = tid & 63, wid = tid >> 6;
    for (int i = tid; i < 8192; i += 256) w_s[i] = W1[i];

    const int r = blockIdx.x * 4 + wid;
    float x = emb[r * 64 + lane];
    float mu = wsum(x) * (1.f / 64.f);
    float xc = x - mu;
    float var = wsum(xc * xc) * (1.f / 64.f);
    float rsig = rsqrtf(var + LN_EPS);
    float xn = xc * rsig * g[lane] + bln[lane];
    xn_s[wid][lane] = xn;
    __syncthreads();

    float a0 = 0.f, a1 = 0.f;
    #pragma unroll
    for (int k = 0; k < 64; ++k) {
        float xnk = xn_s[wid][k];
        a0 = fmaf(xnk, w_s[k * 64 + lane], a0);
        a1 = fmaf(xnk, w_s[(64 + k) * 64 + lane], a1);
    }
    ai[r * 64 + lane] = a0;
    aj[r * 64 + lane] = a1;
}

// ---------------- Kernel 2: LN stats of pairwise products via Gram dots
// mu[b,p,q] = (1/64) sum_k x_p[k] x_q[k];  rs = rsqrt(var + eps)
__global__ __launch_bounds__(128) void att1_stats(
    const float* __restrict__ emb, float* __restrict__ mu, float* __restrict__ rs)
{
    const int bp = blockIdx.x;             // b*128 + p
    const int b = bp >> 7, p = bp & 127;
    const int q = threadIdx.x;
    const float* xp = emb + (b * 128 + p) * 64;
    const float* xq = emb + (b * 128 + q) * 64;
    float s = 0.f, s2 = 0.f;
    #pragma unroll
    for (int k4 = 0; k4 < 16; ++k4) {
        float4 a = ((const float4*)xp)[k4];
        float4 c = ((const float4*)xq)[k4];
        float p0 = a.x * c.x, p1 = a.y * c.y, p2 = a.z * c.z, p3 = a.w * c.w;
        s += p0 + p1 + p2 + p3;
        s2 = fmaf(p0, p0, fmaf(p1, p1, fmaf(p2, p2, fmaf(p3, p3, s2))));
    }
    float m = s * (1.f / 64.f);
    float var = fmaxf(s2 * (1.f / 64.f) - m * m, 0.f);
    mu[bp * 128 + q] = m;
    rs[bp * 128 + q] = rsqrtf(var + LN_EPS);
}

// ---------------- Kernel 3: pack A fragments (bf16 emb in MFMA frag order)
// afrag[b][qt][h][lane][j] = bf16(emb[b, 16*qt+(lane&15), 32*h+8*(lane>>4)+j])
__global__ __launch_bounds__(64) void att1_packA(
    const float* __restrict__ emb, short* __restrict__ afrag)
{
    const int id = blockIdx.x;             // b*16 + qt*2 + h
    const int h = id & 1, qt = (id >> 1) & 7, b = id >> 4;
    const int lane = threadIdx.x;
    const int q = 16 * qt + (lane & 15);
    const int k = 32 * h + 8 * (lane >> 4);
    const float* src = emb + (b * 128 + q) * 64 + k;
    float4 v0 = ((const float4*)src)[0];
    float4 v1 = ((const float4*)src)[1];
    bf16x8 o;
    o[0] = f2bf(v0.x); o[1] = f2bf(v0.y); o[2] = f2bf(v0.z); o[3] = f2bf(v0.w);
    o[4] = f2bf(v1.x); o[5] = f2bf(v1.y); o[6] = f2bf(v1.z); o[7] = f2bf(v1.w);
    *(bf16x8*)(afrag + (size_t)(id * 64 + lane) * 8) = o;
}

// ---------------- Kernel 4: fragment-ordered T[k,d]=g[k]*Wij[k,d] + aux S, c2
__global__ __launch_bounds__(256) void att1_packT(
    const float* __restrict__ g, const float* __restrict__ bln,
    const float* __restrict__ W1, const float* __restrict__ b1,
    float* __restrict__ Tf, float* __restrict__ Sx, float* __restrict__ c2)
{
    const int tid = threadIdx.x;
    for (int slot = tid; slot < 512; slot += 256) {   // (dt*2+h)*64 + lane
        int lane = slot & 63, h = (slot >> 6) & 1, dt = slot >> 7;
        int n = 16 * dt + (lane & 15);
        int k = 32 * h + 8 * (lane >> 4);
        #pragma unroll
        for (int j = 0; j < 8; ++j)
            Tf[slot * 8 + j] = g[k + j] * W1[(128 + k + j) * 64 + n];
    }
    if (tid < 64) {
        float S = 0.f, c = 0.f;
        for (int k = 0; k < 64; ++k) {
            float w = W1[(128 + k) * 64 + tid];
            S = fmaf(g[k], w, S);
            c = fmaf(bln[k], w, c);
        }
        Sx[tid] = S;
        c2[tid] = c + b1[tid];
    }
}

// ---------------- Kernel 5: fused main. Block per (b,p), 8 waves; wave w = qtile w.
__global__ __launch_bounds__(512) void att1_main2(
    const float* __restrict__ emb, const short* __restrict__ afrag,
    const float* __restrict__ Tf, const float* __restrict__ Sx,
    const float* __restrict__ c2a, const float* __restrict__ W2,
    const float* __restrict__ b2, const float* __restrict__ ai,
    const float* __restrict__ aj, const float* __restrict__ mu,
    const float* __restrict__ rs, float* __restrict__ out)
{
    __shared__ float scores_s[128];
    __shared__ float red_s[8][64];

    const int tid = threadIdx.x, lane = tid & 63, w = tid >> 6;
    const int p = blockIdx.x, b = blockIdx.y;
    const int bp = b * 128 + p;
    const float* embB = emb + b * 8192;

    // A fragments for qtile w (coalesced 16B loads, precomputed bf16)
    bf16x8 afr[2];
    afr[0] = *(const bf16x8*)(afrag + (size_t)((b * 8 + w) * 2 + 0) * 512 + lane * 8);
    afr[1] = *(const bf16x8*)(afrag + (size_t)((b * 8 + w) * 2 + 1) * 512 + lane * 8);

    // B fragments: U[k,d] = x_p[k] * T[k,d], built in registers
    bf16x8 bfr[4][2];
    const int kb0 = 8 * (lane >> 4);
    #pragma unroll
    for (int h = 0; h < 2; ++h) {
        const float4* xr = (const float4*)(embB + p * 64 + 32 * h + kb0);
        float4 x0 = xr[0], x1 = xr[1];
        float xpv[8] = {x0.x, x0.y, x0.z, x0.w, x1.x, x1.y, x1.z, x1.w};
        #pragma unroll
        for (int dt = 0; dt < 4; ++dt) {
            const float4* t = (const float4*)(Tf + (size_t)((dt * 2 + h) * 64 + lane) * 8);
            float4 t0 = t[0], t1 = t[1];
            bf16x8 u;
            u[0] = f2bf(t0.x * xpv[0]); u[1] = f2bf(t0.y * xpv[1]);
            u[2] = f2bf(t0.z * xpv[2]); u[3] = f2bf(t0.w * xpv[3]);
            u[4] = f2bf(t1.x * xpv[4]); u[5] = f2bf(t1.y * xpv[5]);
            u[6] = f2bf(t1.z * xpv[6]); u[7] = f2bf(t1.w * xpv[7]);
            bfr[dt][h] = u;
        }
    }

    // MFMA: raw[q = 16w..16w+15, d = 0..63]
    f32x4 acc[4];
    #pragma unroll
    for (int dt = 0; dt < 4; ++dt) {
        f32x4 c = {0.f, 0.f, 0.f, 0.f};
        c = __builtin_amdgcn_mfma_f32_16x16x32_bf16(afr[0], bfr[dt][0], c, 0, 0, 0);
        c = __builtin_amdgcn_mfma_f32_16x16x32_bf16(afr[1], bfr[dt][1], c, 0, 0, 0);
        acc[dt] = c;
    }

    // Epilogue. C/D layout: d = 16*dt + (lane&15), q = 16*w + 4*(lane>>4) + r
    const int g4 = lane >> 4, dl = lane & 15;
    float mu4[4], rs4[4];
    #pragma unroll
    for (int r = 0; r < 4; ++r) {
        int q = 16 * w + 4 * g4 + r;
        mu4[r] = mu[(size_t)bp * 128 + q];
        rs4[r] = rs[(size_t)bp * 128 + q];
    }
    float S4[4], c24[4], w24[4], ajp4[4];
    #pragma unroll
    for (int dt = 0; dt < 4; ++dt) {
        int d = 16 * dt + dl;
        S4[dt] = Sx[d]; c24[dt] = c2a[d]; w24[dt] = W2[d];
        ajp4[dt] = aj[(size_t)bp * 64 + d];
    }
    const float b2s = b2[0];

    float part[4] = {0.f, 0.f, 0.f, 0.f};
    #pragma unroll
    for (int dt = 0; dt < 4; ++dt) {
        #pragma unroll
        for (int r = 0; r < 4; ++r) {
            int q = 16 * w + 4 * g4 + r;
            float aiv = ai[(size_t)(b * 128 + q) * 64 + 16 * dt + dl];
            float x = aiv + ajp4[dt] + rs4[r] * (acc[dt][r] - mu4[r] * S4[dt]) + c24[dt];
            x = fminf(fmaxf(x, -10.f), 10.f);
            float e = __expf(2.f * x);
            float th = (e - 1.f) / (e + 1.f);
            part[r] = fmaf(th, w24[dt], part[r]);
        }
    }
    #pragma unroll
    for (int r = 0; r < 4; ++r) {
        #pragma unroll
        for (int off = 1; off <= 8; off <<= 1)
            part[r] += __shfl_xor(part[r], off, 64);
    }
    if (dl == 0) {
        #pragma unroll
        for (int r = 0; r < 4; ++r)
            scores_s[16 * w + 4 * g4 + r] = part[r] + b2s;
    }
    __syncthreads();

    // Softmax over 128 scores (computed redundantly per wave)
    float s0 = scores_s[lane], s1 = scores_s[64 + lane];
    float M = wmax(fmaxf(s0, s1));
    float Z = wsum(__expf(s0 - M) + __expf(s1 - M));
    float rZ = 1.f / Z;

    // ctx: out[d] = sum_q alpha_q * leaky_relu(x_p[d]*x_q[d])
    float xp_d = embB[p * 64 + lane];
    float accd = 0.f;
    #pragma unroll 4
    for (int i = 0; i < 16; ++i) {
        int q = w + 8 * i;
        float alpha = __expf(scores_s[q] - M) * rZ;
        float prod = xp_d * embB[q * 64 + lane];
        float lr = prod > 0.f ? prod : 0.01f * prod;
        accd = fmaf(alpha, lr, accd);
    }
    red_s[w][lane] = accd;
    __syncthreads();
    if (w == 0) {
        float o = 0.f;
        #pragma unroll
        for (int j = 0; j < 8; ++j) o += red_s[j][lane];
        out[(size_t)bp * 64 + lane] = o;
    }
}

extern "C" void kernel_launch(void* const* d_in, const int* in_sizes, int n_in,
                              void* d_out, int out_size, void* d_ws, size_t ws_size,
                              hipStream_t stream) {
    const float* emb = (const float*)d_in[0];   // [64,128,64]
    const float* g   = (const float*)d_in[1];   // [64]
    const float* bln = (const float*)d_in[2];   // [64]
    const float* W1  = (const float*)d_in[3];   // [192,64]
    const float* b1  = (const float*)d_in[4];   // [64]
    const float* W2  = (const float*)d_in[5];   // [64,1]
    const float* b2  = (const float*)d_in[6];   // [1]
    float* out = (float*)d_out;

    float* ws = (float*)d_ws;
    float* ai = ws;                    // 524288 f
    float* aj = ws + 524288;           // 524288 f
    float* mu = ws + 1048576;          // 1048576 f
    float* rs = ws + 2097152;          // 1048576 f
    float* Tf = ws + 3145728;          // 4096 f
    float* Sx = ws + 3149824;          // 64 f
    float* c2 = ws + 3149888;          // 64 f
    short* af = (short*)(ws + 3149952);// 524288 bf16 (1 MB)

    att1_precompute<<<2048, 256, 0, stream>>>(emb, g, bln, W1, ai, aj);
    att1_stats<<<8192, 128, 0, stream>>>(emb, mu, rs);
    att1_packA<<<1024, 64, 0, stream>>>(emb, af);
    att1_packT<<<1, 256, 0, stream>>>(g, bln, W1, b1, Tf, Sx, c2);
    att1_main2<<<dim3(128, 64), 512, 0, stream>>>(emb, af, Tf, Sx, c2, W2, b2,
                                                  ai, aj, mu, rs, out);
}

// Round 3
// 105.033 us; speedup vs baseline: 3.9679x; 1.5220x over previous
//
#include <hip/hip_runtime.h>

#define LN_EPS 1e-5f
#define S2LE 2.885390081777927f   // 2*log2(e)
#define L2E  1.4426950408889634f  // log2(e)

typedef __attribute__((ext_vector_type(8))) short bf16x8;
typedef __attribute__((ext_vector_type(4))) float f32x4;

__device__ __forceinline__ float wsum(float v) {
    #pragma unroll
    for (int off = 32; off; off >>= 1) v += __shfl_xor(v, off, 64);
    return v;
}
__device__ __forceinline__ float wmax(float v) {
    #pragma unroll
    for (int off = 32; off; off >>= 1) v = fmaxf(v, __shfl_xor(v, off, 64));
    return v;
}
// f32 -> bf16 round-to-nearest-even
__device__ __forceinline__ short f2bf(float f) {
    union { float f; unsigned u; } v; v.f = f;
    unsigned r = (v.u + 0x7FFFu + ((v.u >> 16) & 1u)) >> 16;
    return (short)r;
}
__device__ __forceinline__ float fexp2(float x) {
#if __has_builtin(__builtin_amdgcn_exp2f)
    return __builtin_amdgcn_exp2f(x);
#else
    return exp2f(x);
#endif
}
__device__ __forceinline__ float frcp(float x) {
#if __has_builtin(__builtin_amdgcn_rcpf)
    return __builtin_amdgcn_rcpf(x);
#else
    return 1.f / x;
#endif
}

// ---------------- Kernel 1: ai = S2LE * LN(x)@W1[0:64]; aj = S2LE * LN(x)@W1[64:128]
__global__ __launch_bounds__(256) void att1_precompute(
    const float* __restrict__ emb, const float* __restrict__ g,
    const float* __restrict__ bln, const float* __restrict__ W1,
    float* __restrict__ ai, float* __restrict__ aj)
{
    __shared__ float w_s[8192];
    __shared__ float xn_s[4][64];

    const int tid = threadIdx.x, lane = tid & 63, wid = tid >> 6;
    for (int i = tid; i < 8192; i += 256) w_s[i] = W1[i];

    const int r = blockIdx.x * 4 + wid;
    float x = emb[r * 64 + lane];
    float mu = wsum(x) * (1.f / 64.f);
    float xc = x - mu;
    float var = wsum(xc * xc) * (1.f / 64.f);
    float rsig = rsqrtf(var + LN_EPS);
    float xn = xc * rsig * g[lane] + bln[lane];
    xn_s[wid][lane] = xn;
    __syncthreads();

    float a0 = 0.f, a1 = 0.f;
    #pragma unroll
    for (int k = 0; k < 64; ++k) {
        float xnk = xn_s[wid][k];
        a0 = fmaf(xnk, w_s[k * 64 + lane], a0);
        a1 = fmaf(xnk, w_s[(64 + k) * 64 + lane], a1);
    }
    ai[r * 64 + lane] = a0 * S2LE;
    aj[r * 64 + lane] = a1 * S2LE;
}

// ---------------- Kernel 2: pairwise LN stats via Gram dots (f32 exact path)
// mu[b,p,q] = (1/64) sum_k x_p[k] x_q[k];  rs = S2LE * rsqrt(var + eps)
__global__ __launch_bounds__(128) void att1_stats(
    const float* __restrict__ emb, float* __restrict__ mu, float* __restrict__ rs)
{
    const int bp = blockIdx.x;             // b*128 + p
    const int b = bp >> 7, p = bp & 127;
    const int q = threadIdx.x;
    const float* xp = emb + (b * 128 + p) * 64;
    const float* xq = emb + (b * 128 + q) * 64;
    float s = 0.f, s2 = 0.f;
    #pragma unroll
    for (int k4 = 0; k4 < 16; ++k4) {
        float4 a = ((const float4*)xp)[k4];
        float4 c = ((const float4*)xq)[k4];
        float p0 = a.x * c.x, p1 = a.y * c.y, p2 = a.z * c.z, p3 = a.w * c.w;
        s += p0 + p1 + p2 + p3;
        s2 = fmaf(p0, p0, fmaf(p1, p1, fmaf(p2, p2, fmaf(p3, p3, s2))));
    }
    float m = s * (1.f / 64.f);
    float var = fmaxf(s2 * (1.f / 64.f) - m * m, 0.f);
    mu[bp * 128 + q] = m;
    rs[bp * 128 + q] = rsqrtf(var + LN_EPS) * S2LE;
}

// ---------------- Kernel 3 (merged): pack A fragments + fragment-ordered T + aux
// blocks 0..1023: afrag[b][qt][h][lane][j] = bf16(emb[b, 16qt+(lane&15), 32h+8(lane>>4)+j])
// block 1024:     Tf (frag-ordered g*Wij), Sx, c2 = S2LE*(bln@Wij + b1), consts[0]=sum(W2)+b2
__global__ __launch_bounds__(64) void att1_pack(
    const float* __restrict__ emb, const float* __restrict__ g,
    const float* __restrict__ bln, const float* __restrict__ W1,
    const float* __restrict__ b1, const float* __restrict__ W2,
    const float* __restrict__ b2, short* __restrict__ afrag,
    float* __restrict__ Tf, float* __restrict__ Sx,
    float* __restrict__ c2, float* __restrict__ consts)
{
    const int id = blockIdx.x;
    const int lane = threadIdx.x;
    if (id < 1024) {
        const int h = id & 1, qt = (id >> 1) & 7, b = id >> 4;
        const int q = 16 * qt + (lane & 15);
        const int k = 32 * h + 8 * (lane >> 4);
        const float* src = emb + (b * 128 + q) * 64 + k;
        float4 v0 = ((const float4*)src)[0];
        float4 v1 = ((const float4*)src)[1];
        bf16x8 o;
        o[0] = f2bf(v0.x); o[1] = f2bf(v0.y); o[2] = f2bf(v0.z); o[3] = f2bf(v0.w);
        o[4] = f2bf(v1.x); o[5] = f2bf(v1.y); o[6] = f2bf(v1.z); o[7] = f2bf(v1.w);
        *(bf16x8*)(afrag + (size_t)(id * 64 + lane) * 8) = o;
    } else {
        for (int slot = lane; slot < 512; slot += 64) {
            int l = slot & 63, h = (slot >> 6) & 1, dt = slot >> 7;
            int n = 16 * dt + (l & 15);
            int k = 32 * h + 8 * (l >> 4);
            #pragma unroll
            for (int j = 0; j < 8; ++j)
                Tf[slot * 8 + j] = g[k + j] * W1[(128 + k + j) * 64 + n];
        }
        float S = 0.f, c = 0.f;
        for (int k = 0; k < 64; ++k) {
            float w = W1[(128 + k) * 64 + lane];
            S = fmaf(g[k], w, S);
            c = fmaf(bln[k], w, c);
        }
        Sx[lane] = S;
        c2[lane] = (c + b1[lane]) * S2LE;
        if (lane == 0) {
            float sw = 0.f;
            for (int d = 0; d < 64; ++d) sw += W2[d];
            consts[0] = sw + b2[0];
        }
    }
}

// ---------------- Kernel 4: fused main. Block per (b,p), 8 waves; wave w = q-tile w.
__global__ __launch_bounds__(512) void att1_main(
    const float* __restrict__ emb, const short* __restrict__ afrag,
    const float* __restrict__ Tf, const float* __restrict__ Sx,
    const float* __restrict__ c2a, const float* __restrict__ W2,
    const float* __restrict__ consts, const float* __restrict__ ai,
    const float* __restrict__ aj, const float* __restrict__ mu,
    const float* __restrict__ rs, float* __restrict__ out)
{
    __shared__ bf16x8 bfr_s[512];          // 8 KB: U fragments (shared by all waves)
    __shared__ float scores_s[128];
    __shared__ float red1_s[8][64], red2_s[8][64];

    const int tid = threadIdx.x, lane = tid & 63, w = tid >> 6;
    const int p = blockIdx.x, b = blockIdx.y;
    const int bp = b * 128 + p;
    const float* embB = emb + b * 8192;

    // --- cooperative B-build: this thread builds ONE bf16x8 fragment.
    // slot = tid: lane_s = tid&63, h = (tid>>6)&1, dt = tid>>7
    {
        const int k0 = 32 * ((tid >> 6) & 1) + 8 * ((tid >> 4) & 3);
        const float4* xr = (const float4*)(embB + p * 64 + k0);
        float4 x0 = xr[0], x1 = xr[1];
        const float4* t = (const float4*)(Tf + (size_t)tid * 8);
        float4 t0 = t[0], t1 = t[1];
        bf16x8 u;
        u[0] = f2bf(t0.x * x0.x); u[1] = f2bf(t0.y * x0.y);
        u[2] = f2bf(t0.z * x0.z); u[3] = f2bf(t0.w * x0.w);
        u[4] = f2bf(t1.x * x1.x); u[5] = f2bf(t1.y * x1.y);
        u[6] = f2bf(t1.z * x1.z); u[7] = f2bf(t1.w * x1.w);
        bfr_s[tid] = u;
    }

    // A fragments for q-tile w (precomputed bf16, coalesced 16B loads)
    bf16x8 afr[2];
    afr[0] = *(const bf16x8*)(afrag + (size_t)((b * 16 + 2 * w + 0) * 64 + lane) * 8);
    afr[1] = *(const bf16x8*)(afrag + (size_t)((b * 16 + 2 * w + 1) * 64 + lane) * 8);

    __syncthreads();

    // read back the 8 B fragments (contiguous ds_read_b128, imm offsets)
    bf16x8 bfr[4][2];
    #pragma unroll
    for (int dt = 0; dt < 4; ++dt)
        #pragma unroll
        for (int h = 0; h < 2; ++h)
            bfr[dt][h] = bfr_s[(dt * 2 + h) * 64 + lane];

    // MFMA: raw[q = 16w..16w+15, d = 0..63]
    f32x4 acc[4];
    #pragma unroll
    for (int dt = 0; dt < 4; ++dt) {
        f32x4 c = {0.f, 0.f, 0.f, 0.f};
        c = __builtin_amdgcn_mfma_f32_16x16x32_bf16(afr[0], bfr[dt][0], c, 0, 0, 0);
        c = __builtin_amdgcn_mfma_f32_16x16x32_bf16(afr[1], bfr[dt][1], c, 0, 0, 0);
        acc[dt] = c;
    }

    // Epilogue. C/D layout: d = 16*dt + (lane&15), q = 16*w + 4*(lane>>4) + r
    const int g4 = lane >> 4, dl = lane & 15;
    const int q0 = 16 * w + 4 * g4;
    float4 mu4 = *(const float4*)(mu + (size_t)bp * 128 + q0);
    float4 rs4 = *(const float4*)(rs + (size_t)bp * 128 + q0);
    float muA[4] = {mu4.x, mu4.y, mu4.z, mu4.w};
    float rsA[4] = {rs4.x, rs4.y, rs4.z, rs4.w};
    float rmu[4];
    #pragma unroll
    for (int r = 0; r < 4; ++r) rmu[r] = rsA[r] * muA[r];

    float S4[4], ajc[4], w2m2[4];
    #pragma unroll
    for (int dt = 0; dt < 4; ++dt) {
        int d = 16 * dt + dl;
        S4[dt] = Sx[d];
        ajc[dt] = aj[(size_t)bp * 64 + d] + c2a[d];
        w2m2[dt] = -2.f * W2[d];
    }

    // scores: sum_d w2*tanh(x) = sum(w2) - sum_d 2*w2 / (2^{x'} + 1), x' prescaled
    const float* aibase = ai + (size_t)(b * 128 + q0) * 64 + dl;
    float part[4] = {0.f, 0.f, 0.f, 0.f};
    #pragma unroll
    for (int dt = 0; dt < 4; ++dt) {
        #pragma unroll
        for (int r = 0; r < 4; ++r) {
            float aiv = aibase[r * 64 + dt * 16];
            float xv = fmaf(rsA[r], acc[dt][r], fmaf(-rmu[r], S4[dt], ajc[dt]) + aiv);
            float e = fexp2(xv);
            part[r] = fmaf(w2m2[dt], frcp(e + 1.f), part[r]);
        }
    }
    #pragma unroll
    for (int r = 0; r < 4; ++r) {
        #pragma unroll
        for (int off = 1; off <= 8; off <<= 1)
            part[r] += __shfl_xor(part[r], off, 64);
    }
    const float sw2b2 = consts[0];
    if (dl == 0) {
        float4 sc = {part[0] + sw2b2, part[1] + sw2b2, part[2] + sw2b2, part[3] + sw2b2};
        *(float4*)&scores_s[q0] = sc;
    }
    __syncthreads();

    // softmax over 128 scores (redundant per wave; cheap)
    float s0 = scores_s[lane], s1 = scores_s[64 + lane];
    float M = wmax(fmaxf(s0, s1));
    float Z = wsum(fexp2((s0 - M) * L2E) + fexp2((s1 - M) * L2E));
    float rZ = frcp(Z);

    // ctx via lrelu(v) = 0.505 v + 0.495 |v|:
    // out[d] = rZ * (0.505*xp[d]*sum_q e_q*xq[d] + 0.495*|xp[d]|*sum_q e_q*|xq[d]|)
    const float mML = -M * L2E;
    const float* xqb = embB + 16 * w * 64 + lane;
    float s1acc = 0.f, s2acc = 0.f;
    #pragma unroll
    for (int i = 0; i < 16; ++i) {
        float al = fexp2(fmaf(scores_s[16 * w + i], L2E, mML));
        float xq = xqb[i * 64];
        s1acc = fmaf(al, xq, s1acc);
        s2acc = fmaf(al, fabsf(xq), s2acc);
    }
    red1_s[w][lane] = s1acc;
    red2_s[w][lane] = s2acc;
    __syncthreads();
    if (w == 0) {
        float S1 = 0.f, S2 = 0.f;
        #pragma unroll
        for (int j = 0; j < 8; ++j) { S1 += red1_s[j][lane]; S2 += red2_s[j][lane]; }
        float xp = embB[p * 64 + lane];
        out[(size_t)bp * 64 + lane] = rZ * fmaf(0.505f * xp, S1, 0.495f * fabsf(xp) * S2);
    }
}

extern "C" void kernel_launch(void* const* d_in, const int* in_sizes, int n_in,
                              void* d_out, int out_size, void* d_ws, size_t ws_size,
                              hipStream_t stream) {
    const float* emb = (const float*)d_in[0];   // [64,128,64]
    const float* g   = (const float*)d_in[1];   // [64]
    const float* bln = (const float*)d_in[2];   // [64]
    const float* W1  = (const float*)d_in[3];   // [192,64]
    const float* b1  = (const float*)d_in[4];   // [64]
    const float* W2  = (const float*)d_in[5];   // [64,1]
    const float* b2  = (const float*)d_in[6];   // [1]
    float* out = (float*)d_out;

    float* ws = (float*)d_ws;
    float* ai = ws;                      // 524288 f
    float* aj = ws + 524288;             // 524288 f
    float* mu = ws + 1048576;            // 1048576 f
    float* rs = ws + 2097152;            // 1048576 f
    float* Tf = ws + 3145728;            // 4096 f
    float* Sx = ws + 3149824;            // 64 f
    float* c2 = ws + 3149888;            // 64 f
    float* consts = ws + 3149952;        // 64 f (1 used)
    short* af = (short*)(ws + 3150016);  // 524288 bf16 (1 MB)

    att1_precompute<<<2048, 256, 0, stream>>>(emb, g, bln, W1, ai, aj);
    att1_stats<<<8192, 128, 0, stream>>>(emb, mu, rs);
    att1_pack<<<1025, 64, 0, stream>>>(emb, g, bln, W1, b1, W2, b2, af, Tf, Sx, c2, consts);
    att1_main<<<dim3(128, 64), 512, 0, stream>>>(emb, af, Tf, Sx, c2, W2, consts,
                                                 ai, aj, mu, rs, out);
}

// Round 4
// 75.983 us; speedup vs baseline: 5.4850x; 1.3823x over previous
//
#include <hip/hip_runtime.h>

#define LN_EPS 1e-5f
#define S2LE 2.885390081777927f   // 2*log2(e)
#define L2E  1.4426950408889634f  // log2(e)
#define XST 68                    // LDS row stride for x tile (68 mod 32 = 4 -> bank spread)

typedef __attribute__((ext_vector_type(8))) short bf16x8;
typedef __attribute__((ext_vector_type(4))) float f32x4;

__device__ __forceinline__ float wsum(float v) {
    #pragma unroll
    for (int off = 32; off; off >>= 1) v += __shfl_xor(v, off, 64);
    return v;
}
__device__ __forceinline__ float wmax(float v) {
    #pragma unroll
    for (int off = 32; off; off >>= 1) v = fmaxf(v, __shfl_xor(v, off, 64));
    return v;
}
// f32 -> bf16 round-to-nearest-even
__device__ __forceinline__ short f2bf(float f) {
    union { float f; unsigned u; } v; v.f = f;
    unsigned r = (v.u + 0x7FFFu + ((v.u >> 16) & 1u)) >> 16;
    return (short)r;
}
__device__ __forceinline__ float fexp2(float x) {
#if __has_builtin(__builtin_amdgcn_exp2f)
    return __builtin_amdgcn_exp2f(x);
#else
    return exp2f(x);
#endif
}
__device__ __forceinline__ float frcp(float x) {
#if __has_builtin(__builtin_amdgcn_rcpf)
    return __builtin_amdgcn_rcpf(x);
#else
    return 1.f / x;
#endif
}

// ================= prep: 769 blocks x 256 threads, roles by blockIdx =================
// blocks 0..511   : ai/aj (16 rows each, 4 waves x 4 iters), prescaled by S2LE
// blocks 512..767 : afrag pack (4 fragment-slots per block)
// block 768       : Tf (frag-ordered g*Wij), Sx, c2, consts[0]=sum(W2)+b2
__global__ __launch_bounds__(256) void att1_prep(
    const float* __restrict__ emb, const float* __restrict__ g,
    const float* __restrict__ bln, const float* __restrict__ W1,
    const float* __restrict__ b1, const float* __restrict__ W2,
    const float* __restrict__ b2, float* __restrict__ ai,
    float* __restrict__ aj, short* __restrict__ afrag,
    float* __restrict__ Tf, float* __restrict__ Sx,
    float* __restrict__ c2, float* __restrict__ consts)
{
    const int bid = blockIdx.x, tid = threadIdx.x, lane = tid & 63, wid = tid >> 6;
    if (bid < 512) {
        __shared__ float w_s[8192];
        __shared__ float xn_s[4][64];   // per-wave private
        for (int i = tid * 4; i < 8192; i += 1024)
            *(float4*)&w_s[i] = *(const float4*)&W1[i];
        __syncthreads();
        #pragma unroll
        for (int it = 0; it < 4; ++it) {
            const int r = bid * 16 + it * 4 + wid;
            float x = emb[r * 64 + lane];
            float m = wsum(x) * (1.f / 64.f);
            float xc = x - m;
            float var = wsum(xc * xc) * (1.f / 64.f);
            float xn = xc * rsqrtf(var + LN_EPS) * g[lane] + bln[lane];
            xn_s[wid][lane] = xn;          // same-wave write->read, no barrier needed
            float a0 = 0.f, a1 = 0.f;
            #pragma unroll
            for (int k = 0; k < 64; ++k) {
                float xnk = xn_s[wid][k];
                a0 = fmaf(xnk, w_s[k * 64 + lane], a0);
                a1 = fmaf(xnk, w_s[(64 + k) * 64 + lane], a1);
            }
            ai[r * 64 + lane] = a0 * S2LE;
            aj[r * 64 + lane] = a1 * S2LE;
        }
    } else if (bid < 768) {
        const int id = (bid - 512) * 4 + wid;      // b*16 + qt*2 + h
        const int h = id & 1, qt = (id >> 1) & 7, b = id >> 4;
        const int q = 16 * qt + (lane & 15);
        const int k = 32 * h + 8 * (lane >> 4);
        const float* src = emb + (b * 128 + q) * 64 + k;
        float4 v0 = ((const float4*)src)[0];
        float4 v1 = ((const float4*)src)[1];
        bf16x8 o;
        o[0] = f2bf(v0.x); o[1] = f2bf(v0.y); o[2] = f2bf(v0.z); o[3] = f2bf(v0.w);
        o[4] = f2bf(v1.x); o[5] = f2bf(v1.y); o[6] = f2bf(v1.z); o[7] = f2bf(v1.w);
        *(bf16x8*)(afrag + (size_t)(id * 64 + lane) * 8) = o;
    } else {
        for (int slot = tid; slot < 512; slot += 256) {   // (dt*2+h)*64 + l
            int l = slot & 63, h = (slot >> 6) & 1, dt = slot >> 7;
            int n = 16 * dt + (l & 15);
            int k = 32 * h + 8 * (l >> 4);
            #pragma unroll
            for (int j = 0; j < 8; ++j)
                Tf[slot * 8 + j] = g[k + j] * W1[(128 + k + j) * 64 + n];
        }
        if (tid < 64) {
            float S = 0.f, c = 0.f;
            for (int k = 0; k < 64; ++k) {
                float w = W1[(128 + k) * 64 + tid];
                S = fmaf(g[k], w, S);
                c = fmaf(bln[k], w, c);
            }
            Sx[tid] = S;
            c2[tid] = (c + b1[tid]) * S2LE;
            if (tid == 0) {
                float sw = 0.f;
                for (int d = 0; d < 64; ++d) sw += W2[d];
                consts[0] = sw + b2[0];
            }
        }
    }
}

// ================= main: block per (b,p), 8 waves; wave w = q-tile w =================
__global__ __launch_bounds__(512) void att1_main(
    const float* __restrict__ emb, const short* __restrict__ afrag,
    const float* __restrict__ Tf, const float* __restrict__ Sx,
    const float* __restrict__ c2a, const float* __restrict__ W2,
    const float* __restrict__ consts, const float* __restrict__ ai,
    const float* __restrict__ aj, float* __restrict__ out)
{
    __shared__ float xb_s[128 * XST];      // 34 KB: emb[b] rows, stride 68
    __shared__ bf16x8 bfr_s[512];          // 8 KB: U fragments
    __shared__ float mu_s[128], rs_s[128];
    __shared__ float scores_s[128], alpha_s[128];
    __shared__ float red1_s[8][64], red2_s[8][64];

    const int tid = threadIdx.x, lane = tid & 63, w = tid >> 6;
    const int p = blockIdx.x, b = blockIdx.y;
    const int bp = b * 128 + p;
    const float* embB = emb + b * 8192;

    // A fragments (global, L2-hot, issue early)
    bf16x8 afr0 = *(const bf16x8*)(afrag + (size_t)((b * 16 + 2 * w + 0) * 64 + lane) * 8);
    bf16x8 afr1 = *(const bf16x8*)(afrag + (size_t)((b * 16 + 2 * w + 1) * 64 + lane) * 8);

    // stage emb[b] into LDS (stride 68)
    {
        const int r0 = tid >> 4, c0 = (tid & 15) * 4;
        #pragma unroll
        for (int pass = 0; pass < 4; ++pass) {
            int r = r0 + pass * 32;
            *(float4*)&xb_s[r * XST + c0] = *(const float4*)&embB[r * 64 + c0];
        }
    }
    __syncthreads();

    // --- B-build: one bf16x8 U fragment per thread
    {
        const int k0 = 32 * ((tid >> 6) & 1) + 8 * ((tid >> 4) & 3);
        const float* xr = &xb_s[p * XST + k0];
        float4 x0 = *(const float4*)xr, x1 = *(const float4*)(xr + 4);
        const float4* t = (const float4*)(Tf + (size_t)tid * 8);
        float4 t0 = t[0], t1 = t[1];
        bf16x8 u;
        u[0] = f2bf(t0.x * x0.x); u[1] = f2bf(t0.y * x0.y);
        u[2] = f2bf(t0.z * x0.z); u[3] = f2bf(t0.w * x0.w);
        u[4] = f2bf(t1.x * x1.x); u[5] = f2bf(t1.y * x1.y);
        u[6] = f2bf(t1.z * x1.z); u[7] = f2bf(t1.w * x1.w);
        bfr_s[tid] = u;
    }

    // --- stats: pair q = tid>>2, k-quarter c = tid&3 (f32, exact)
    {
        const int q = tid >> 2, c = tid & 3;
        const float* xq = &xb_s[q * XST + c * 16];
        const float* xp = &xb_s[p * XST + c * 16];
        float s = 0.f, s2 = 0.f;
        #pragma unroll
        for (int j = 0; j < 4; ++j) {
            float4 a = *(const float4*)(xp + j * 4);
            float4 d = *(const float4*)(xq + j * 4);
            float p0 = a.x * d.x, p1 = a.y * d.y, p2 = a.z * d.z, p3 = a.w * d.w;
            s += p0 + p1 + p2 + p3;
            s2 = fmaf(p0, p0, fmaf(p1, p1, fmaf(p2, p2, fmaf(p3, p3, s2))));
        }
        s  += __shfl_xor(s, 1, 64);  s  += __shfl_xor(s, 2, 64);
        s2 += __shfl_xor(s2, 1, 64); s2 += __shfl_xor(s2, 2, 64);
        if (c == 0) {
            float m = s * (1.f / 64.f);
            float var = fmaxf(s2 * (1.f / 64.f) - m * m, 0.f);
            mu_s[q] = m;
            rs_s[q] = rsqrtf(var + LN_EPS) * S2LE;
        }
    }
    __syncthreads();

    // --- MFMA: raw[q = 16w..16w+15, d = 0..63]
    bf16x8 bfr[4][2];
    #pragma unroll
    for (int dt = 0; dt < 4; ++dt)
        #pragma unroll
        for (int h = 0; h < 2; ++h)
            bfr[dt][h] = bfr_s[(dt * 2 + h) * 64 + lane];

    f32x4 acc[4];
    #pragma unroll
    for (int dt = 0; dt < 4; ++dt) {
        f32x4 c = {0.f, 0.f, 0.f, 0.f};
        c = __builtin_amdgcn_mfma_f32_16x16x32_bf16(afr0, bfr[dt][0], c, 0, 0, 0);
        c = __builtin_amdgcn_mfma_f32_16x16x32_bf16(afr1, bfr[dt][1], c, 0, 0, 0);
        acc[dt] = c;
    }

    // --- epilogue. C/D layout: d = 16*dt + (lane&15), q = 16*w + 4*(lane>>4) + r
    const int g4 = lane >> 4, dl = lane & 15;
    const int q0 = 16 * w + 4 * g4;
    float4 mu4 = *(const float4*)&mu_s[q0];
    float4 rs4 = *(const float4*)&rs_s[q0];
    float muA[4] = {mu4.x, mu4.y, mu4.z, mu4.w};
    float rsA[4] = {rs4.x, rs4.y, rs4.z, rs4.w};
    float rmu[4];
    #pragma unroll
    for (int r = 0; r < 4; ++r) rmu[r] = rsA[r] * muA[r];

    float S4[4], ajc[4], w2m2[4];
    #pragma unroll
    for (int dt = 0; dt < 4; ++dt) {
        int d = 16 * dt + dl;
        S4[dt] = Sx[d];
        ajc[dt] = aj[(size_t)bp * 64 + d] + c2a[d];
        w2m2[dt] = -2.f * W2[d];
    }

    // scores: sum_d w2*tanh = sum(w2) - sum_d 2*w2 / (2^{x'} + 1), x' prescaled
    const float* aibase = ai + (size_t)(b * 128 + q0) * 64 + dl;
    float part[4] = {0.f, 0.f, 0.f, 0.f};
    #pragma unroll
    for (int dt = 0; dt < 4; ++dt) {
        #pragma unroll
        for (int r = 0; r < 4; ++r) {
            float aiv = aibase[r * 64 + dt * 16];
            float xv = fmaf(rsA[r], acc[dt][r], fmaf(-rmu[r], S4[dt], ajc[dt]) + aiv);
            float e = fexp2(xv);
            part[r] = fmaf(w2m2[dt], frcp(e + 1.f), part[r]);
        }
    }
    #pragma unroll
    for (int r = 0; r < 4; ++r) {
        #pragma unroll
        for (int off = 1; off <= 8; off <<= 1)
            part[r] += __shfl_xor(part[r], off, 64);
    }
    const float sw2b2 = consts[0];
    if (dl == 0) {
        float4 sc = {part[0] + sw2b2, part[1] + sw2b2, part[2] + sw2b2, part[3] + sw2b2};
        *(float4*)&scores_s[q0] = sc;
    }
    __syncthreads();

    // --- softmax + alpha (waves 0,1 only; alpha includes 1/Z)
    if (w < 2) {
        float s0 = scores_s[lane], s1 = scores_s[64 + lane];
        float M = wmax(fmaxf(s0, s1));
        float Z = wsum(fexp2((s0 - M) * L2E) + fexp2((s1 - M) * L2E));
        float rZ = frcp(Z);
        float sown = (w == 0) ? s0 : s1;
        alpha_s[tid] = fexp2((sown - M) * L2E) * rZ;
    }
    __syncthreads();

    // --- ctx via lrelu(v) = 0.505 v + 0.495 |v|
    float s1acc = 0.f, s2acc = 0.f;
    #pragma unroll
    for (int i = 0; i < 16; ++i) {
        int q = 16 * w + i;
        float al = alpha_s[q];                 // broadcast
        float xq = xb_s[q * XST + lane];       // conflict-free row read
        s1acc = fmaf(al, xq, s1acc);
        s2acc = fmaf(al, fabsf(xq), s2acc);
    }
    red1_s[w][lane] = s1acc;
    red2_s[w][lane] = s2acc;
    __syncthreads();
    if (w == 0) {
        float S1 = 0.f, S2 = 0.f;
        #pragma unroll
        for (int j = 0; j < 8; ++j) { S1 += red1_s[j][lane]; S2 += red2_s[j][lane]; }
        float xp = xb_s[p * XST + lane];
        out[(size_t)bp * 64 + lane] = fmaf(0.505f * xp, S1, 0.495f * fabsf(xp) * S2);
    }
}

extern "C" void kernel_launch(void* const* d_in, const int* in_sizes, int n_in,
                              void* d_out, int out_size, void* d_ws, size_t ws_size,
                              hipStream_t stream) {
    const float* emb = (const float*)d_in[0];   // [64,128,64]
    const float* g   = (const float*)d_in[1];   // [64]
    const float* bln = (const float*)d_in[2];   // [64]
    const float* W1  = (const float*)d_in[3];   // [192,64]
    const float* b1  = (const float*)d_in[4];   // [64]
    const float* W2  = (const float*)d_in[5];   // [64,1]
    const float* b2  = (const float*)d_in[6];   // [1]
    float* out = (float*)d_out;

    float* ws = (float*)d_ws;
    float* ai = ws;                      // 524288 f
    float* aj = ws + 524288;             // 524288 f
    float* Tf = ws + 1048576;            // 4096 f
    float* Sx = ws + 1052672;            // 64 f
    float* c2 = ws + 1052736;            // 64 f
    float* consts = ws + 1052800;        // 64 f (1 used)
    short* af = (short*)(ws + 1052864);  // 524288 bf16 (1 MB)

    att1_prep<<<769, 256, 0, stream>>>(emb, g, bln, W1, b1, W2, b2,
                                       ai, aj, af, Tf, Sx, c2, consts);
    att1_main<<<dim3(128, 64), 512, 0, stream>>>(emb, af, Tf, Sx, c2, W2, consts,
                                                 ai, aj, out);
}